// Round 1
// baseline (552.999 us; speedup 1.0000x reference)
//
#include <hip/hip_runtime.h>

#define NF     256
#define NPAIRS 32640
#define OUTW   (NF + NPAIRS)   // 32896
#define BATCH  4096

__global__ __launch_bounds__(256)
void poly_features_kernel(const float* __restrict__ x,
                          const int*   __restrict__ idx_a,
                          const int*   __restrict__ idx_b,
                          float*       __restrict__ out)
{
    __shared__ float sx[NF];

    const int b = blockIdx.x;
    const int t = threadIdx.x;

    const float* xrow = x + (size_t)b * NF;
    float v = xrow[t];
    sx[t] = v;

    float* orow = out + (size_t)b * OUTW;
    orow[t] = v;                       // identity part, coalesced

    __syncthreads();

    const int4* ia4 = (const int4*)idx_a;
    const int4* ib4 = (const int4*)idx_b;
    float4* o4 = (float4*)(orow + NF); // 16B-aligned: (b*32896+256)*4 % 16 == 0

    #pragma unroll 4
    for (int g = t; g < NPAIRS / 4; g += 256) {
        int4 ia = ia4[g];
        int4 ib = ib4[g];
        float4 r;
        r.x = sx[ia.x] * sx[ib.x];
        r.y = sx[ia.y] * sx[ib.y];
        r.z = sx[ia.z] * sx[ib.z];
        r.w = sx[ia.w] * sx[ib.w];
        o4[g] = r;
    }
}

extern "C" void kernel_launch(void* const* d_in, const int* in_sizes, int n_in,
                              void* d_out, int out_size, void* d_ws, size_t ws_size,
                              hipStream_t stream) {
    const float* x     = (const float*)d_in[0];
    const int*   idx_a = (const int*)d_in[1];
    const int*   idx_b = (const int*)d_in[2];
    float*       out   = (float*)d_out;

    poly_features_kernel<<<BATCH, 256, 0, stream>>>(x, idx_a, idx_b, out);
}